// Round 1
// baseline (2620.283 us; speedup 1.0000x reference)
//
#include <hip/hip_runtime.h>
#include <math.h>

namespace {

constexpr int TT  = 192;   // timesteps
constexpr int INp = 24;    // input features
constexpr int Hh  = 64;    // hidden
constexpr int Kk  = 20;    // spline knots
constexpr int NG  = 4 * Hh;      // 256 gates per layer
constexpr int BB  = 8;           // batch rows per block
constexpr int NBLK = 2048 / BB;  // 256 blocks

__device__ __forceinline__ float sigmoidf_(float x) {
  return 1.0f / (1.0f + __expf(-x));
}
__device__ __forceinline__ float tanhf_(float x) {
  // 2*sigmoid(2x)-1, stable at both tails
  return 2.0f / (1.0f + __expf(-2.0f * x)) - 1.0f;
}
__device__ __forceinline__ float softplusf_(float x) {
  // max(x,0) + log1p(exp(-|x|))  (matches jax.nn.softplus = logaddexp(x,0))
  return fmaxf(x, 0.0f) + log1pf(__expf(-fabsf(x)));
}

__global__ __launch_bounds__(256, 1) void lstm_crps_kernel(
    const float* __restrict__ train,   // [2048,192,24]
    const float* __restrict__ labels,  // [2048,192]
    const float* __restrict__ w_ih0,   // [256,24]
    const float* __restrict__ w_hh0,   // [256,64]
    const float* __restrict__ b_ih0,   // [256]
    const float* __restrict__ b_hh0,   // [256]
    const float* __restrict__ w_ih1,   // [256,64]
    const float* __restrict__ w_hh1,   // [256,64]
    const float* __restrict__ b_ih1,   // [256]
    const float* __restrict__ b_hh1,   // [256]
    const float* __restrict__ w_b0,    // [1,128]
    const float* __restrict__ bb_b0,   // [1]
    const float* __restrict__ w_g,     // [20,128]
    const float* __restrict__ b_g,     // [20]
    float* __restrict__ partials)      // [NBLK]
{
  __shared__ __align__(16) float x_l[BB][INp];     // 24 floats/row, 96B rows (16B aligned)
  __shared__ __align__(16) float h0_l[BB][68];     // pad 68 to break bank conflicts in proj
  __shared__ __align__(16) float h1_l[BB][68];
  __shared__ __align__(16) float gates_l[BB][NG];
  __shared__ float bg_l[BB][22];                   // [0]=beta0, [1..20]=gamma
  __shared__ __align__(16) float wproj[21][132];   // row o: weights over 128 interleaved feats
  __shared__ float pbias[21];
  __shared__ float labels_l[BB][TT];
  __shared__ float red_l[256];

  const int tid = (int)threadIdx.x;
  const int r0  = (int)blockIdx.x * BB;

  // ---- per-thread gate-row weights (statically indexed -> VGPRs) ----
  float wih0[INp], whh0[Hh], wih1[Hh], whh1[Hh];
  {
    const float* p = w_ih0 + (size_t)tid * INp;
#pragma unroll
    for (int k = 0; k < INp; ++k) wih0[k] = p[k];
  }
  {
    const float* p = w_hh0 + (size_t)tid * Hh;
#pragma unroll
    for (int k = 0; k < Hh; ++k) whh0[k] = p[k];
  }
  {
    const float* p = w_ih1 + (size_t)tid * Hh;
#pragma unroll
    for (int k = 0; k < Hh; ++k) wih1[k] = p[k];
  }
  {
    const float* p = w_hh1 + (size_t)tid * Hh;
#pragma unroll
    for (int k = 0; k < Hh; ++k) whh1[k] = p[k];
  }
  const float bias0 = b_ih0[tid] + b_hh0[tid];
  const float bias1 = b_ih1[tid] + b_hh1[tid];

  // ---- projection weights -> LDS (row 0 = w_b0, rows 1..20 = w_g) ----
  for (int i = tid; i < 21 * 128; i += 256) {
    int o = i >> 7, kk2 = i & 127;
    wproj[o][kk2] = (o == 0) ? w_b0[kk2] : w_g[(size_t)(o - 1) * 128 + kk2];
  }
  if (tid < 21) pbias[tid] = (tid == 0) ? bb_b0[0] : b_g[tid - 1];

  // ---- labels for this block's rows ----
  for (int i = tid; i < BB * TT; i += 256) {
    int r = i / TT, t = i % TT;
    labels_l[r][t] = labels[(size_t)(r0 + r) * TT + t];
  }
  // ---- zero hidden state ----
  for (int i = tid; i < BB * 68; i += 256) {
    (&h0_l[0][0])[i] = 0.0f;
    (&h1_l[0][0])[i] = 0.0f;
  }

  // cell-state registers: thread handles rows (rA, rA+4) for column jj
  const int jj = tid & 63;
  const int rA = tid >> 6;   // 0..3
  const int rB = rA + 4;
  float c0A = 0.0f, c0B = 0.0f, c1A = 0.0f, c1B = 0.0f;

  // x prefetch registers
  const int xi_r = tid / INp, xi_k = tid % INp;
  float xr = 0.0f;
  if (tid < BB * INp) xr = train[((size_t)(r0 + xi_r) * TT + 0) * INp + xi_k];

  const float sig = 1.0f / (float)Kk;
  // per-lane ksi = foldl(+, 0, l copies of sig) -> matches jnp.cumsum fidelity
  const int lcr = tid & 31;
  float myksi = 0.0f;
  for (int i = 0; i < lcr && i < Kk; ++i) myksi += sig;

  float cacc = 0.0f;

  __syncthreads();

  for (int t = 0; t < TT; ++t) {
    // phase 1: publish x(t)
    if (tid < BB * INp) x_l[xi_r][xi_k] = xr;
    __syncthreads();  // B1
    if (tid < BB * INp && (t + 1) < TT)
      xr = train[((size_t)(r0 + xi_r) * TT + (t + 1)) * INp + xi_k];

    float acc[BB];

    // ---- layer 0 gates ----
#pragma unroll
    for (int r = 0; r < BB; ++r) acc[r] = bias0;
#pragma unroll
    for (int kc = 0; kc < INp / 4; ++kc) {
#pragma unroll
      for (int r = 0; r < BB; ++r) {
        float4 v = *reinterpret_cast<const float4*>(&x_l[r][kc * 4]);
        acc[r] += wih0[kc * 4 + 0] * v.x + wih0[kc * 4 + 1] * v.y +
                  wih0[kc * 4 + 2] * v.z + wih0[kc * 4 + 3] * v.w;
      }
    }
#pragma unroll
    for (int kc = 0; kc < Hh / 4; ++kc) {
#pragma unroll
      for (int r = 0; r < BB; ++r) {
        float4 v = *reinterpret_cast<const float4*>(&h0_l[r][kc * 4]);
        acc[r] += whh0[kc * 4 + 0] * v.x + whh0[kc * 4 + 1] * v.y +
                  whh0[kc * 4 + 2] * v.z + whh0[kc * 4 + 3] * v.w;
      }
    }
#pragma unroll
    for (int r = 0; r < BB; ++r) gates_l[r][tid] = acc[r];
    __syncthreads();  // B2

    // ---- layer 0 cell update ----
    {
      float gi = gates_l[rA][jj], gf = gates_l[rA][64 + jj];
      float gg = gates_l[rA][128 + jj], go = gates_l[rA][192 + jj];
      float c2 = sigmoidf_(gf) * c0A + sigmoidf_(gi) * tanhf_(gg);
      c0A = c2;
      h0_l[rA][jj] = sigmoidf_(go) * tanhf_(c2);
      gi = gates_l[rB][jj]; gf = gates_l[rB][64 + jj];
      gg = gates_l[rB][128 + jj]; go = gates_l[rB][192 + jj];
      c2 = sigmoidf_(gf) * c0B + sigmoidf_(gi) * tanhf_(gg);
      c0B = c2;
      h0_l[rB][jj] = sigmoidf_(go) * tanhf_(c2);
    }
    __syncthreads();  // B3

    // ---- layer 1 gates (input = new h0) ----
#pragma unroll
    for (int r = 0; r < BB; ++r) acc[r] = bias1;
#pragma unroll
    for (int kc = 0; kc < Hh / 4; ++kc) {
#pragma unroll
      for (int r = 0; r < BB; ++r) {
        float4 v = *reinterpret_cast<const float4*>(&h0_l[r][kc * 4]);
        acc[r] += wih1[kc * 4 + 0] * v.x + wih1[kc * 4 + 1] * v.y +
                  wih1[kc * 4 + 2] * v.z + wih1[kc * 4 + 3] * v.w;
      }
    }
#pragma unroll
    for (int kc = 0; kc < Hh / 4; ++kc) {
#pragma unroll
      for (int r = 0; r < BB; ++r) {
        float4 v = *reinterpret_cast<const float4*>(&h1_l[r][kc * 4]);
        acc[r] += whh1[kc * 4 + 0] * v.x + whh1[kc * 4 + 1] * v.y +
                  whh1[kc * 4 + 2] * v.z + whh1[kc * 4 + 3] * v.w;
      }
    }
#pragma unroll
    for (int r = 0; r < BB; ++r) gates_l[r][tid] = acc[r];
    __syncthreads();  // B4

    // ---- layer 1 cell update ----
    {
      float gi = gates_l[rA][jj], gf = gates_l[rA][64 + jj];
      float gg = gates_l[rA][128 + jj], go = gates_l[rA][192 + jj];
      float c2 = sigmoidf_(gf) * c1A + sigmoidf_(gi) * tanhf_(gg);
      c1A = c2;
      h1_l[rA][jj] = sigmoidf_(go) * tanhf_(c2);
      gi = gates_l[rB][jj]; gf = gates_l[rB][64 + jj];
      gg = gates_l[rB][128 + jj]; go = gates_l[rB][192 + jj];
      c2 = sigmoidf_(gf) * c1B + sigmoidf_(gi) * tanhf_(gg);
      c1B = c2;
      h1_l[rB][jj] = sigmoidf_(go) * tanhf_(c2);
    }
    __syncthreads();  // B5

    // ---- projection + softplus: feats[b][2h+l] = h_l[b][h] ----
    if (tid < BB * 21) {
      int o = tid >> 3, r = tid & 7;
      float lin = pbias[o];
#pragma unroll 16
      for (int h = 0; h < Hh; ++h) {
        float2 wv = *reinterpret_cast<const float2*>(&wproj[o][2 * h]);
        lin += h0_l[r][h] * wv.x + h1_l[r][h] * wv.y;
      }
      bg_l[r][o] = softplusf_(lin);
    }
    __syncthreads();  // B6

    // ---- CRPS: one 32-lane group per row ----
    {
      const int grp = tid >> 5;  // row 0..7
      const int l = tid & 31;
      const bool valid = (l < Kk);
      const float y = labels_l[grp][t];
      const float b0v = bg_l[grp][0];

      float braw = 0.0f;
      if (valid) {
        float gam = bg_l[grp][1 + l];  // gamma[l]
        float bp  = bg_l[grp][l];      // l==0 ? beta0 : gamma[l-1]
        braw = (gam - bp) / (2.0f * sig);
      }
      float brawm1 = __shfl_up(braw, 1, 32);
      float bj = valid ? (braw - ((l == 0) ? 0.0f : brawm1)) : 0.0f;
      // replace last: b[K-1] = gamma[K-1] - sum(b[0..K-2])
      float st = (l < Kk - 1) ? bj : 0.0f;
#pragma unroll
      for (int off = 16; off > 0; off >>= 1) st += __shfl_xor(st, off, 32);
      if (l == Kk - 1) bj = bg_l[grp][Kk] - st;

      // knots[i] = b0*ksi_i + sum_j b_j * max(ksi_i - ksi_j, 0)^2
      float knot = b0v * myksi;
      float kj = 0.0f;
#pragma unroll
      for (int j = 0; j < Kk; ++j) {
        float bjj = __shfl(bj, j, 32);
        float d = fmaxf(myksi - kj, 0.0f);
        knot += bjj * d * d;
        kj += sig;
      }
      float diff = y - knot;
      bool al = valid && (diff > 0.0f);
      float ab = al ? bj : 0.0f;
      float tA = ab;
      float tB = ab * myksi;
      float tC = ab * myksi * myksi;
      float u = 1.0f - myksi;
      float c3t = valid ? (bj * (1.0f / 6.0f)) * (u * u * u * u) : 0.0f;
      float ad = valid ? fabsf(diff) : 3.4e38f;
      int ai = l;
#pragma unroll
      for (int off = 16; off > 0; off >>= 1) {
        tA += __shfl_xor(tA, off, 32);
        tB += __shfl_xor(tB, off, 32);
        tC += __shfl_xor(tC, off, 32);
        c3t += __shfl_xor(c3t, off, 32);
        float oad = __shfl_xor(ad, off, 32);
        int   oai = __shfl_xor(ai, off, 32);
        if (oad < ad || (oad == ad && oai < ai)) { ad = oad; ai = oai; }
      }
      float A   = tA;
      float Bco = b0v - 2.0f * tB;
      float Cc  = -y + tC;
      float disc = Bco * Bco - 4.0f * A * Cc;
      float ksi_pick = __shfl(myksi, ai, 32);
      float A_safe = (A != 0.0f) ? A : 1.0f;
      float B_safe = (Bco != 0.0f) ? Bco : 1.0f;
      float quad = (-Bco + sqrtf(fmaxf(disc, 0.0f))) / (2.0f * A_safe);
      float alpha = (A != 0.0f && disc >= 0.0f)
                        ? quad
                        : ((A == 0.0f) ? (-Cc / B_safe) : ksi_pick);
      float dk = alpha - myksi;
      float c4t = al ? ((2.0f / 3.0f) * bj) * (dk * dk * dk) : 0.0f;
#pragma unroll
      for (int off = 16; off > 0; off >>= 1) c4t += __shfl_xor(c4t, off, 32);
      float crps = y * (2.0f * alpha - 1.0f) +
                   b0v * ((1.0f / 3.0f) - alpha * alpha) + c3t - c4t;
      if (l == 0) cacc += crps;
    }
    // no barrier needed here: next iter's x_l write doesn't alias CRPS reads,
    // and B1..B6 separate all other producer/consumer pairs across iterations
  }

  // ---- block reduction ----
  red_l[tid] = cacc;
  __syncthreads();
#pragma unroll
  for (int s = 128; s > 0; s >>= 1) {
    if (tid < s) red_l[tid] += red_l[tid + s];
    __syncthreads();
  }
  if (tid == 0) partials[blockIdx.x] = red_l[0];
}

__global__ void final_reduce_kernel(const float* __restrict__ partials,
                                    float* __restrict__ out) {
  __shared__ float s_l[NBLK];
  const int tid = (int)threadIdx.x;
  s_l[tid] = partials[tid];
  __syncthreads();
  for (int s = NBLK / 2; s > 0; s >>= 1) {
    if (tid < s) s_l[tid] += s_l[tid + s];
    __syncthreads();
  }
  if (tid == 0) out[0] = s_l[0] * (1.0f / 2048.0f);
}

}  // namespace

extern "C" void kernel_launch(void* const* d_in, const int* in_sizes, int n_in,
                              void* d_out, int out_size, void* d_ws, size_t ws_size,
                              hipStream_t stream) {
  (void)in_sizes; (void)n_in; (void)out_size; (void)ws_size;
  const float* train  = (const float*)d_in[0];
  const float* labels = (const float*)d_in[1];
  const float* w_ih0  = (const float*)d_in[2];
  const float* w_hh0  = (const float*)d_in[3];
  const float* b_ih0  = (const float*)d_in[4];
  const float* b_hh0  = (const float*)d_in[5];
  const float* w_ih1  = (const float*)d_in[6];
  const float* w_hh1  = (const float*)d_in[7];
  const float* b_ih1  = (const float*)d_in[8];
  const float* b_hh1  = (const float*)d_in[9];
  const float* w_b0   = (const float*)d_in[10];
  const float* bb_b0  = (const float*)d_in[11];
  const float* w_g    = (const float*)d_in[12];
  const float* b_g    = (const float*)d_in[13];

  float* partials = (float*)d_ws;

  lstm_crps_kernel<<<dim3(NBLK), dim3(256), 0, stream>>>(
      train, labels, w_ih0, w_hh0, b_ih0, b_hh0, w_ih1, w_hh1, b_ih1, b_hh1,
      w_b0, bb_b0, w_g, b_g, partials);
  final_reduce_kernel<<<dim3(1), dim3(NBLK), 0, stream>>>(partials,
                                                          (float*)d_out);
}